// Round 3
// baseline (1012.934 us; speedup 1.0000x reference)
//
#include <hip/hip_runtime.h>
#include <hip/hip_bf16.h>
#include <cstdint>

#define LATN 16
#define LONGN 12
#define PP 192          // LAT*LONG positions per n
#define CIN 128
#define CMID 128
#define EPSV 1e-5f
#define SPLIT 4         // blocks per n (channel split)
#define CHB 32          // channels per block
#define CST 193         // LDS channel stride (floats): odd -> conflict-free scatter

typedef float v2f __attribute__((ext_vector_type(2)));

// ---------------- counting sort of scatter records by destination n ----------------

__global__ void count_kernel(const int* __restrict__ pidx, int* __restrict__ counts, int E) {
    int e = blockIdx.x * 256 + threadIdx.x;
    if (e >= E) return;
#pragma unroll
    for (int i = 0; i < 4; i++) {
        int v = pidx[i * E + e];
        int n = v / PP;
        atomicAdd(&counts[n], 1);
    }
}

// single block, 1024 threads, N <= 4096. counts may alias cur.
__global__ void scan_kernel(const int* __restrict__ counts, int* __restrict__ start,
                            int* __restrict__ cur, int N) {
    __shared__ int sdata[1024];
    int tid = threadIdx.x;
    int c[4];
    int s = 0;
#pragma unroll
    for (int j = 0; j < 4; j++) {
        int idx = tid * 4 + j;
        c[j] = (idx < N) ? counts[idx] : 0;
        s += c[j];
    }
    sdata[tid] = s;
    __syncthreads();
    for (int off = 1; off < 1024; off <<= 1) {
        int t = (tid >= off) ? sdata[tid - off] : 0;
        __syncthreads();
        sdata[tid] += t;
        __syncthreads();
    }
    int excl = sdata[tid] - s;
#pragma unroll
    for (int j = 0; j < 4; j++) {
        int idx = tid * 4 + j;
        if (idx < N) { start[idx] = excl; cur[idx] = excl; }
        excl += c[j];
    }
    if (tid == 1023) start[N] = sdata[1023];
}

// emit bucketed records: rec.x = src | (p<<18), rec.y = delta bits
__global__ void record_kernel(const int* __restrict__ pidx, const int* __restrict__ src_idx,
                              const float* __restrict__ delta, int* __restrict__ cur,
                              uint2* __restrict__ rec, int E) {
    int e = blockIdx.x * 256 + threadIdx.x;
    if (e >= E) return;
    int src = src_idx[e];
#pragma unroll
    for (int i = 0; i < 4; i++) {
        int v = pidx[i * E + e];
        int n = v / PP;
        int p = v - n * PP;
        int pos = atomicAdd(&cur[n], 1);
        rec[pos] = make_uint2((uint32_t)src | ((uint32_t)p << 18),
                              __float_as_uint(delta[i * E + e]));
    }
}

// transpose conv weights [o][i][k] -> [i][k][o]
__global__ void wt_kernel(const float* __restrict__ w, float* __restrict__ wt, int total) {
    int id = blockIdx.x * 256 + threadIdx.x;
    if (id >= total) return;
    int o = id / (CIN * LONGN);
    int rem = id - o * (CIN * LONGN);
    int i = rem / LONGN;
    int k = rem - i * LONGN;
    wt[(i * LONGN + k) * CMID + o] = w[id];
}

// ---------------- fused: scatter->LDS tile (transposed), conv, silu, pool, groupnorm ----

__global__ __launch_bounds__(256, 5) void fused_kernel(
    const float* __restrict__ x, const uint2* __restrict__ rec,
    const int* __restrict__ start, const float* __restrict__ wt,
    const float* __restrict__ conv_b, const float* __restrict__ gn_w,
    const float* __restrict__ gn_b, float* __restrict__ out) {
    __shared__ float tile[CHB * CST];       // transposed: tile[c*CST + lat*12 + long]

    int bid = blockIdx.x;
    int n = bid >> 2;
    int b = bid & 3;
    int tid = threadIdx.x;

    for (int i = tid; i < CHB * CST; i += 256) tile[i] = 0.f;
    __syncthreads();

    // ---- scatter: half-wave per record, coalesced 128-B x row reads ----
    int b0 = start[n], b1 = start[n + 1];
    {
        int c = tid & 31;                   // local channel = lane
        int slot = tid >> 5;                // 8 records in flight
        int cg = b * CHB + c;               // global channel
        for (int it = b0 + slot; it < b1; it += 8) {
            uint2 rv = rec[it];
            float dl = __uint_as_float(rv.y);
            int src = (int)(rv.x & 0x3FFFFu);
            int p = (int)(rv.x >> 18);
            float xv = x[(size_t)src * CIN + cg];
            atomicAdd(&tile[c * CST + p], xv * dl);
        }
    }
    __syncthreads();

    // ---- grouped circular conv: thread = (o_local = tid>>3, q = tid&7) ----
    int o_local = tid >> 3;                 // 0..31 (4 groups of 8)
    int q = tid & 7;                        // in-channel-within-group (sphere c)
    int gl = o_local >> 3;                  // local group 0..3 (== wave id)
    int c = gl * 8 + q;                     // local tile channel
    int o = b * CHB + o_local;              // global out channel

    const float* trow = tile + c * CST;
    const float* wbase = wt + (size_t)(q * LATN * LONGN) * CMID + o;  // i = q*16+lat

    v2f acc2[6];
#pragma unroll
    for (int i = 0; i < 6; i++) acc2[i] = (v2f)(0.f);

    float wc[12];
#pragma unroll
    for (int k = 0; k < 12; k++) wc[k] = wbase[k * CMID];

#pragma unroll
    for (int lat = 0; lat < LATN; lat++) {
        float wn[12];
        if (lat < LATN - 1) {
            const float* wb = wbase + (size_t)((lat + 1) * LONGN) * CMID;
#pragma unroll
            for (int k = 0; k < 12; k++) wn[k] = wb[k * CMID];
        }
        const float* r = trow + lat * LONGN;
        float rv[12];
#pragma unroll
        for (int j = 0; j < 12; j++) rv[j] = r[j];
        v2f rp[12];
#pragma unroll
        for (int j = 0; j < 12; j++) { rp[j].x = rv[j]; rp[j].y = rv[(j + 1) % 12]; }
#pragma unroll
        for (int k = 0; k < 12; k++) {
            v2f w2 = (v2f)(wc[k]);
#pragma unroll
            for (int t2 = 0; t2 < 6; t2++)
                acc2[t2] += w2 * rp[(k + 2 * t2 + 6) % 12];   // +6: circular pad shift
        }
        if (lat < LATN - 1) {
#pragma unroll
            for (int k = 0; k < 12; k++) wc[k] = wn[k];
        }
    }

    // ---- reduce over q via shfl butterfly (lane bits 0..2) ----
    float av[12];
#pragma unroll
    for (int t2 = 0; t2 < 6; t2++) { av[2 * t2] = acc2[t2].x; av[2 * t2 + 1] = acc2[t2].y; }
#pragma unroll
    for (int m = 1; m < 8; m <<= 1) {
#pragma unroll
        for (int t = 0; t < 12; t++) av[t] += __shfl_xor(av[t], m);
    }

    // ---- silu + pool (all lanes redundantly per 8-lane q-group) ----
    float bias = conv_b[o];
    float sv = 0.f;
#pragma unroll
    for (int t = 0; t < 12; t++) {
        float z = av[t] + bias;
        sv += z / (1.f + __expf(-z));
    }
    sv *= (1.f / 12.f);

    // ---- GroupNorm: group = 8 o's = lane bits 3..5 of this wave ----
    float s1 = sv, s2 = sv * sv;
#pragma unroll
    for (int m = 8; m < 64; m <<= 1) {
        s1 += __shfl_xor(s1, m);
        s2 += __shfl_xor(s2, m);
    }
    float mu = s1 * 0.125f;
    float var = s2 * 0.125f - mu * mu;
    var = fmaxf(var, 0.f);
    float inv = rsqrtf(var + EPSV);
    if (q == 0) {
        out[(size_t)n * CMID + o] = (sv - mu) * inv * gn_w[o] + gn_b[o];
    }
}

extern "C" void kernel_launch(void* const* d_in, const int* in_sizes, int n_in,
                              void* d_out, int out_size, void* d_ws, size_t ws_size,
                              hipStream_t stream) {
    const float* x = (const float*)d_in[0];
    const int* pidx = (const int*)d_in[2];
    const float* delta = (const float*)d_in[3];
    const int* src_idx = (const int*)d_in[4];
    const float* conv_w = (const float*)d_in[5];
    const float* conv_b = (const float*)d_in[6];
    const float* gn_w = (const float*)d_in[7];
    const float* gn_b = (const float*)d_in[8];
    float* out = (float*)d_out;

    int E = in_sizes[0] / CIN;          // 200000
    int N = out_size / CMID;            // 4096

    char* ws = (char*)d_ws;
    size_t off = 0;
    auto alloc = [&](size_t bytes) {
        size_t cur = off;
        off = (off + bytes + 255) & ~(size_t)255;
        return cur;
    };
    int* cur = (int*)(ws + alloc((size_t)N * 4));
    int* start = (int*)(ws + alloc((size_t)(N + 1) * 4));
    uint2* rec = (uint2*)(ws + alloc((size_t)4 * E * 8));
    float* wt = (float*)(ws + alloc((size_t)CMID * CIN * LONGN * 4));

    hipMemsetAsync(cur, 0, (size_t)N * 4, stream);

    int gE = (E + 255) / 256;
    count_kernel<<<gE, 256, 0, stream>>>(pidx, cur, E);
    scan_kernel<<<1, 1024, 0, stream>>>(cur, start, cur, N);
    record_kernel<<<gE, 256, 0, stream>>>(pidx, src_idx, delta, cur, rec, E);
    int totW = CMID * CIN * LONGN;
    wt_kernel<<<(totW + 255) / 256, 256, 0, stream>>>(conv_w, wt, totW);
    fused_kernel<<<N * SPLIT, 256, 0, stream>>>(x, rec, start, wt, conv_b, gn_w, gn_b, out);
}

// Round 4
// 727.847 us; speedup vs baseline: 1.3917x; 1.3917x over previous
//
#include <hip/hip_runtime.h>
#include <hip/hip_bf16.h>
#include <cstdint>

#define LATN 16
#define LONGN 12
#define PP 192          // LAT*LONG positions per n
#define CIN 128
#define CMID 128
#define EPSV 1e-5f
#define SPLIT 4         // blocks per n (channel split)
#define CHB 32          // channels per block
#define TSTRIDE 33      // padded LDS tile row stride (floats)

typedef float v2f __attribute__((ext_vector_type(2)));

// ---------------- counting sort of scatter records by destination n ----------------

__global__ void count_kernel(const int* __restrict__ pidx, int* __restrict__ counts, int E) {
    int e = blockIdx.x * 256 + threadIdx.x;
    if (e >= E) return;
#pragma unroll
    for (int i = 0; i < 4; i++) {
        int v = pidx[i * E + e];
        int n = v / PP;
        atomicAdd(&counts[n], 1);
    }
}

// single block, 1024 threads, N <= 4096. counts may alias cur.
__global__ void scan_kernel(const int* __restrict__ counts, int* __restrict__ start,
                            int* __restrict__ cur, int N) {
    __shared__ int sdata[1024];
    int tid = threadIdx.x;
    int c[4];
    int s = 0;
#pragma unroll
    for (int j = 0; j < 4; j++) {
        int idx = tid * 4 + j;
        c[j] = (idx < N) ? counts[idx] : 0;
        s += c[j];
    }
    sdata[tid] = s;
    __syncthreads();
    for (int off = 1; off < 1024; off <<= 1) {
        int t = (tid >= off) ? sdata[tid - off] : 0;
        __syncthreads();
        sdata[tid] += t;
        __syncthreads();
    }
    int excl = sdata[tid] - s;
#pragma unroll
    for (int j = 0; j < 4; j++) {
        int idx = tid * 4 + j;
        if (idx < N) { start[idx] = excl; cur[idx] = excl; }
        excl += c[j];
    }
    if (tid == 1023) start[N] = sdata[1023];
}

// emit bucketed records: rec.x = src | (p<<18), rec.y = delta bits
__global__ void record_kernel(const int* __restrict__ pidx, const int* __restrict__ src_idx,
                              const float* __restrict__ delta, int* __restrict__ cur,
                              uint2* __restrict__ rec, int E) {
    int e = blockIdx.x * 256 + threadIdx.x;
    if (e >= E) return;
    int src = src_idx[e];
#pragma unroll
    for (int i = 0; i < 4; i++) {
        int v = pidx[i * E + e];
        int n = v / PP;
        int p = v - n * PP;
        int pos = atomicAdd(&cur[n], 1);
        rec[pos] = make_uint2((uint32_t)src | ((uint32_t)p << 18),
                              __float_as_uint(delta[i * E + e]));
    }
}

// transpose conv weights [o][i][k] -> [i][k][o] for lane-coalesced loads
__global__ void wt_kernel(const float* __restrict__ w, float* __restrict__ wt, int total) {
    int id = blockIdx.x * 256 + threadIdx.x;
    if (id >= total) return;
    int o = id / (CIN * LONGN);
    int rem = id - o * (CIN * LONGN);
    int i = rem / LONGN;
    int k = rem - i * LONGN;
    wt[(i * LONGN + k) * CMID + o] = w[id];
}

// ---------------- fused: scatter->LDS tile, conv, silu, pool, groupnorm ----------------
// One block handles 32 channels (= 4 GroupNorm groups) of one n.

__global__ __launch_bounds__(256, 6) void fused_kernel(
    const float* __restrict__ x, const uint2* __restrict__ rec,
    const int* __restrict__ start, const float* __restrict__ wt,
    const float* __restrict__ conv_b, const float* __restrict__ gn_w,
    const float* __restrict__ gn_b, float* __restrict__ out) {
    __shared__ float tile[PP * TSTRIDE];    // 25344 B

    int bid = blockIdx.x;
    int n = bid >> 2;
    int b = bid & 3;
    int tid = threadIdx.x;

    // zero tile (float4: 1584 vectors)
    {
        float4* t4 = (float4*)tile;
        for (int i = tid; i < PP * TSTRIDE / 4; i += 256)
            t4[i] = float4{0.f, 0.f, 0.f, 0.f};
    }
    __syncthreads();

    // ---- scatter: 8 lanes/record (float4), 4-deep software pipeline ----
    int b0 = start[n], b1 = start[n + 1];
    {
        int il = tid & 7;                   // lane within record: 4 channels each
        int slot = tid >> 3;                // 0..31
        int cbase = b * CHB + il * 4;       // global channel of this lane's float4
        for (int it = b0 + slot; it < b1; it += 32 * 4) {
            uint2 rv[4];
            float4 xv[4];
            int idx[4];
#pragma unroll
            for (int u = 0; u < 4; u++) {
                idx[u] = it + u * 32;
                if (idx[u] < b1) rv[u] = rec[idx[u]];
            }
#pragma unroll
            for (int u = 0; u < 4; u++) {
                if (idx[u] < b1) {
                    int src = (int)(rv[u].x & 0x3FFFFu);
                    xv[u] = *(const float4*)(x + (size_t)src * CIN + cbase);
                }
            }
#pragma unroll
            for (int u = 0; u < 4; u++) {
                if (idx[u] < b1) {
                    float dl = __uint_as_float(rv[u].y);
                    int p = (int)(rv[u].x >> 18);
                    float* trow = tile + p * TSTRIDE + il * 4;
                    atomicAdd(trow + 0, xv[u].x * dl);
                    atomicAdd(trow + 1, xv[u].y * dl);
                    atomicAdd(trow + 2, xv[u].z * dl);
                    atomicAdd(trow + 3, xv[u].w * dl);
                }
            }
        }
    }
    __syncthreads();

    // ---- grouped circular conv: thread = (q = tid>>5, o_local = tid&31) ----
    int o_local = tid & 31;
    int q = tid >> 5;                       // 0..7 = in-channel-within-group
    int g_local = o_local >> 3;             // 0..3
    int o = b * CHB + o_local;              // global out channel
    int ch_local = g_local * 8 + q;         // tile channel (within block)

    v2f acc2[6];
#pragma unroll
    for (int u = 0; u < 6; u++) acc2[u] = (v2f)(0.f);

#pragma unroll
    for (int lat = 0; lat < LATN; lat++) {
        float r[12];
#pragma unroll
        for (int j = 0; j < 12; j++)
            r[j] = tile[(lat * LONGN + ((j + 6) % 12)) * TSTRIDE + ch_local];
        v2f rp[12];
#pragma unroll
        for (int j = 0; j < 12; j++) { rp[j].x = r[j]; rp[j].y = r[(j + 1) % 12]; }
        int i = q * LATN + lat;             // conv in-channel within group
        const float* wrow = wt + (size_t)(i * LONGN) * CMID + o;
#pragma unroll
        for (int k = 0; k < 12; k++) {
            float wv = wrow[k * CMID];
            v2f w2 = {wv, wv};
#pragma unroll
            for (int u = 0; u < 6; u++)
                acc2[u] += w2 * rp[(k + 2 * u) % 12];
        }
    }
    __syncthreads();

    // ---- reduce partials across q (LDS), silu, pool, groupnorm ----
    float* pbuf = tile;                     // 8*12*32 = 3072 floats
#pragma unroll
    for (int u = 0; u < 6; u++) {
        pbuf[(q * 12 + 2 * u) * 32 + o_local] = acc2[u].x;
        pbuf[(q * 12 + 2 * u + 1) * 32 + o_local] = acc2[u].y;
    }
    __syncthreads();

    float* gbuf = tile + 8 * 12 * 32;       // 32 floats
    float sv = 0.f;
    if (tid < 32) {
        float bias = conv_b[b * CHB + tid];
#pragma unroll
        for (int t = 0; t < 12; t++) {
            float z = bias;
#pragma unroll
            for (int qq = 0; qq < 8; qq++) z += pbuf[(qq * 12 + t) * 32 + tid];
            sv += z / (1.f + __expf(-z));
        }
        sv *= (1.f / 12.f);
        gbuf[tid] = sv;
    }
    __syncthreads();
    if (tid < 32) {
        int gb = tid & ~7;
        float mu = 0.f, m2 = 0.f;
#pragma unroll
        for (int j = 0; j < 8; j++) {
            float v = gbuf[gb + j];
            mu += v;
            m2 += v * v;
        }
        mu *= 0.125f;
        float var = m2 * 0.125f - mu * mu;
        var = fmaxf(var, 0.f);
        float inv = rsqrtf(var + EPSV);
        int oc = b * CHB + tid;
        out[(size_t)n * CMID + oc] = (sv - mu) * inv * gn_w[oc] + gn_b[oc];
    }
}

extern "C" void kernel_launch(void* const* d_in, const int* in_sizes, int n_in,
                              void* d_out, int out_size, void* d_ws, size_t ws_size,
                              hipStream_t stream) {
    const float* x = (const float*)d_in[0];
    const int* pidx = (const int*)d_in[2];
    const float* delta = (const float*)d_in[3];
    const int* src_idx = (const int*)d_in[4];
    const float* conv_w = (const float*)d_in[5];
    const float* conv_b = (const float*)d_in[6];
    const float* gn_w = (const float*)d_in[7];
    const float* gn_b = (const float*)d_in[8];
    float* out = (float*)d_out;

    int E = in_sizes[0] / CIN;          // 200000
    int N = out_size / CMID;            // 4096

    char* ws = (char*)d_ws;
    size_t off = 0;
    auto alloc = [&](size_t bytes) {
        size_t cur = off;
        off = (off + bytes + 255) & ~(size_t)255;
        return cur;
    };
    int* cur = (int*)(ws + alloc((size_t)N * 4));
    int* start = (int*)(ws + alloc((size_t)(N + 1) * 4));
    uint2* rec = (uint2*)(ws + alloc((size_t)4 * E * 8));
    float* wt = (float*)(ws + alloc((size_t)CMID * CIN * LONGN * 4));

    hipMemsetAsync(cur, 0, (size_t)N * 4, stream);

    int gE = (E + 255) / 256;
    count_kernel<<<gE, 256, 0, stream>>>(pidx, cur, E);
    scan_kernel<<<1, 1024, 0, stream>>>(cur, start, cur, N);
    record_kernel<<<gE, 256, 0, stream>>>(pidx, src_idx, delta, cur, rec, E);
    int totW = CMID * CIN * LONGN;
    wt_kernel<<<(totW + 255) / 256, 256, 0, stream>>>(conv_w, wt, totW);
    fused_kernel<<<N * SPLIT, 256, 0, stream>>>(x, rec, start, wt, conv_b, gn_w, gn_b, out);
}